// Round 5
// baseline (233.825 us; speedup 1.0000x reference)
//
#include <hip/hip_runtime.h>

// KrausRK4 via bf16 MFMA, r5: ping-pong software pipelining of jump-sum loops
// + phase folding: 58 -> 28 barrier phases at constant LDS (40KB, 4 blocks/CU).
// phys(row, cbyte) = row*128 + (((cbyte>>4) ^ ((row>>3)&7))<<4) + (cbyte&15)

typedef __attribute__((ext_vector_type(16))) float f32x16;
typedef __attribute__((ext_vector_type(8))) __bf16 bf16x8;

#define MATB 8192

__device__ __forceinline__ unsigned short bf16rne(float x) {
  unsigned u = __builtin_bit_cast(unsigned, x);
  return (unsigned short)((u + 0x7FFFu + ((u >> 16) & 1u)) >> 16);
}
__device__ __forceinline__ float bflo(unsigned u) {
  return __builtin_bit_cast(float, u << 16);
}
__device__ __forceinline__ float bfhi(unsigned u) {
  return __builtin_bit_cast(float, u & 0xFFFF0000u);
}

// acc += P @ Q^T, P = operator frags (global), Q = LDS matrix rows (swizzled)
__device__ __forceinline__ void mm4_gl(f32x16& acc, const char* __restrict__ gP,
                                       const char* ldsQ, int vq, int lh) {
#pragma unroll
  for (int s = 0; s < 4; ++s) {
    bf16x8 a = *(const bf16x8*)(gP + s * 1024);
    bf16x8 b = *(const bf16x8*)(ldsQ + (((2 * s + lh) ^ vq) << 4));
    acc = __builtin_amdgcn_mfma_f32_32x32x16_bf16(a, b, acc, 0, 0, 0);
  }
}
// acc += P @ Q^T, P = LDS matrix rows (swizzled), Q = operator frags (global)
__device__ __forceinline__ void mm4_lg(f32x16& acc, const char* ldsP, int vp,
                                       int lh, const char* __restrict__ gQ) {
#pragma unroll
  for (int s = 0; s < 4; ++s) {
    bf16x8 a = *(const bf16x8*)(ldsP + (((2 * s + lh) ^ vp) << 4));
    bf16x8 b = *(const bf16x8*)(gQ + s * 1024);
    acc = __builtin_amdgcn_mfma_f32_32x32x16_bf16(a, b, acc, 0, 0, 0);
  }
}

// write 32x32 C-tile (row-major, swizzled): row = ti*32+4lh+(r&3)+8(r>>2)
__device__ __forceinline__ void wtile(char* base, int ti, int slotc, int coff,
                                      int lh, const f32x16& v) {
#pragma unroll
  for (int r = 0; r < 16; ++r) {
    int row = ti * 32 + 4 * lh + (r & 3) + 8 * (r >> 2);
    int ps = (slotc ^ ((4 * ti + (r >> 2)) & 7)) << 4;
    *(unsigned short*)(base + row * 128 + ps + coff) = bf16rne(v[r]);
  }
}
__device__ __forceinline__ void wtile_rmw(char* base, int ti, int slotc, int coff,
                                          int lh, const f32x16& v, float s) {
#pragma unroll
  for (int r = 0; r < 16; ++r) {
    int row = ti * 32 + 4 * lh + (r & 3) + 8 * (r >> 2);
    int ps = (slotc ^ ((4 * ti + (r >> 2)) & 7)) << 4;
    unsigned short* p = (unsigned short*)(base + row * 128 + ps + coff);
    float old = bflo((unsigned)*p);
    *p = bf16rne(old + s * v[r]);
  }
}

// D = A + s*B elementwise on raw swizzled dwords (2048 per matrix)
__device__ __forceinline__ void axpy(char* D, const char* A, float s,
                                     const char* B, int tid) {
#pragma unroll
  for (int j = 0; j < 8; ++j) {
    int off = (tid + 256 * j) * 4;
    unsigned a = *(const unsigned*)(A + off);
    unsigned b = *(const unsigned*)(B + off);
    float lo = bflo(a) + s * bflo(b);
    float hi = bfhi(a) + s * bfhi(b);
    *(unsigned*)(D + off) = (unsigned)bf16rne(lo) | ((unsigned)bf16rne(hi) << 16);
  }
}

// ---------------- Um1 = U1 @ inv(Um), fp32 Gauss-Jordan, no pivot -----------
__global__ __launch_bounds__(256) void kraus_invert(
    const float* __restrict__ U1, const float* __restrict__ Um,
    float* __restrict__ Um1) {
  __shared__ float M[64][66];
  __shared__ float X[64][66];
  int tid = threadIdx.x;
#pragma unroll
  for (int it = 0; it < 16; ++it) {
    int idx = tid + 256 * it;
    int r = idx >> 6, c = idx & 63;
    M[r][c] = Um[idx];
    X[r][c] = (r == c) ? 1.0f : 0.0f;
  }
  __syncthreads();
  for (int k = 0; k < 64; ++k) {
    if (tid < 64) {
      float ip = 1.0f / M[k][k];   // all lanes read before lane k writes
      M[k][tid] *= ip;
      X[k][tid] *= ip;
    }
    __syncthreads();
    int r = tid & 63, q = tid >> 6;
    float f = M[r][k];
    __syncthreads();
    if (r != k) {
#pragma unroll
      for (int cc = 0; cc < 16; ++cc) {
        int c = q * 16 + cc;
        M[r][c] -= f * M[k][c];
        X[r][c] -= f * X[k][c];
      }
    }
    __syncthreads();
  }
  for (int it = 0; it < 16; ++it) {
    int idx = tid + 256 * it;
    int i = idx >> 6, j = idx & 63;
    float s = 0.0f;
#pragma unroll 4
    for (int k = 0; k < 64; ++k) s += U1[i * 64 + k] * X[k][j];
    Um1[idx] = s;
  }
}

// ---------------- prepack: 15 operators -> bf16 fragment-major in ws --------
// op order: 0=U1 1=Um 2=Um1 3..6=Ls0 7..10=Lsmid 11..14=Ls1
// frag elem: d[o*4096 + f*512 + l*8 + i] = M[t*32+(l&31)][s*16+(l>>5)*8+i], f=t*4+s
__global__ __launch_bounds__(256) void kraus_prepack(
    const float* __restrict__ U1, const float* __restrict__ Um,
    const float* __restrict__ Ls0, const float* __restrict__ Lsmid,
    const float* __restrict__ Ls1, float* __restrict__ ws) {
  const float* Um1 = ws;
  unsigned short* dst = (unsigned short*)((char*)ws + 16384);
  int o = blockIdx.x;
  const float* s;
  if (o == 0) s = U1;
  else if (o == 1) s = Um;
  else if (o == 2) s = Um1;
  else if (o < 7) s = Ls0 + (o - 3) * 4096;
  else if (o < 11) s = Lsmid + (o - 7) * 4096;
  else s = Ls1 + (o - 11) * 4096;
  unsigned short* d = dst + o * 4096;
  int tid = threadIdx.x;
#pragma unroll
  for (int j = 0; j < 16; ++j) {
    int idx = tid + 256 * j;
    int f = idx >> 9, l = (idx >> 3) & 63, i = idx & 7;
    int t = f >> 2, ss = f & 3;
    int R = t * 32 + (l & 31);
    int C = ss * 16 + (l >> 5) * 8 + i;
    d[idx] = bf16rne(s[R * 64 + C]);
  }
}

// ---------------- main kernel: one block per batch item, 28 phases ----------
__global__ __launch_bounds__(256, 4) void kraus_main(
    const float* __restrict__ rho0g, const float* __restrict__ dtp,
    const char* __restrict__ gfrag, float* __restrict__ outg) {
  __shared__ __align__(16) char lds[5 * MATB];   // 40960 B -> 4 blocks/CU
  char* B0 = lds;              // hat(rho0) -> Shat -> hat(rho3) -> t4
  char* B1 = B0 + MATB;        // ping(J0) -> tA -> hat(P) -> hat(rho4)
  char* B3 = B1 + MATB;        // t_rho2 -> ping(J2/J3) -> tJJ
  char* B4 = B3 + MATB;        // hat(T) -> hat(rho2) -> hat(J2) -> ping(Jf)
  char* TMP = B4 + MATB;       // ping / hat(J0) / tS / hat(J3)

  const int tid = threadIdx.x;
  const int l = tid & 63, w = tid >> 6;
  const int ti = w >> 1, tj = w & 1;
  const int l31 = l & 31, lh = l >> 5;
  const int vA = (4 * ti + (l31 >> 3)) & 7;
  const int vB = (4 * tj + (l31 >> 3)) & 7;
  const int rA = (ti * 32 + l31) * 128;
  const int rB = (tj * 32 + l31) * 128;
  const int slotc = 4 * tj + (l31 >> 3), coff = (l31 & 7) * 2;
  const float dt = dtp[0];
  const size_t b = blockIdx.x;
  const char* gA0 = gfrag + ti * 4096 + l * 16;
  const char* gB0 = gfrag + tj * 4096 + l * 16;

  auto GL = [&](f32x16& acc, int op, const char* q) {
    mm4_gl(acc, gA0 + op * 8192, q + rB, vB, lh);
  };
  auto LG = [&](f32x16& acc, const char* p, int op) {
    mm4_lg(acc, p + rA, vA, lh, gB0 + op * 8192);
  };
  auto WT = [&](char* dst, const f32x16& v) { wtile(dst, ti, slotc, coff, lh, v); };

  // ph1: stage hat(rho0) -> B0 (swizzled)
  {
    const float* src = rho0g + b * 4096 + tid * 16;
    float vals[16];
#pragma unroll
    for (int q = 0; q < 4; ++q) {
      float4 f = *(const float4*)(src + q * 4);
      vals[q * 4 + 0] = f.x; vals[q * 4 + 1] = f.y;
      vals[q * 4 + 2] = f.z; vals[q * 4 + 3] = f.w;
    }
    int r = tid >> 2, c0 = (tid & 3) * 16;
    int sr = r >> 3, cr = (r & 7) * 2;
#pragma unroll
    for (int u = 0; u < 16; ++u) {
      int row = c0 + u;
      int ps = (sr ^ ((row >> 3) & 7)) << 4;
      *(unsigned short*)(B0 + row * 128 + ps + cr) = bf16rne(vals[u]);
    }
  }
  __syncthreads();

  f32x16 outacc = {};

  // J0 loop (src B0, ping TMP/B1), hat(J0) -> TMP          [ph2..ph6]
  {
    f32x16 J = {};
    { f32x16 t = {}; GL(t, 3, B0); WT(TMP, t); } __syncthreads();
    { f32x16 t = {}; GL(J, 3, TMP); GL(t, 4, B0); WT(B1, t); } __syncthreads();
    { f32x16 t = {}; GL(J, 4, B1); GL(t, 5, B0); WT(TMP, t); } __syncthreads();
    { f32x16 t = {}; GL(J, 5, TMP); GL(t, 6, B0); WT(B1, t); } __syncthreads();
    { GL(J, 6, B1); WT(TMP, J); } __syncthreads();
  }

  // ph7: tA = U1@J0 -> B1 ; hat(T) = hat(rho0) + 0.5dt*hat(J0) -> B4
  { f32x16 t = {}; GL(t, 0, TMP); WT(B1, t); axpy(B4, B0, 0.5f * dt, TMP, tid); }
  __syncthreads();

  // ph8: out += dt/6 * tA@U1^T ; tP = U1@rho0 -> TMP
  { f32x16 s = {}; LG(s, B1, 0); outacc += (dt / 6.f) * s;
    f32x16 t = {}; GL(t, 0, B0); WT(TMP, t); }
  __syncthreads();

  // ph9: out += tP@U1^T ; hat(P) = U1@tP^T -> B1 ; t_rho2 = Um@T -> B3
  { f32x16 s = {}; LG(s, TMP, 0); outacc += s;
    f32x16 p = {}; GL(p, 0, TMP); WT(B1, p);
    f32x16 t = {}; GL(t, 1, B4); WT(B3, t); }
  __syncthreads();

  // ph10: hat(rho2) = Um@t_rho2^T -> B4 ; tS = Um@rho0 -> TMP
  { f32x16 r2 = {}; GL(r2, 1, B3); WT(B4, r2);
    f32x16 t = {}; GL(t, 1, B0); WT(TMP, t); }
  __syncthreads();

  // ph11: Shat = Um@tS^T -> B0 ; t0 = M0@rho2 -> B3
  { f32x16 s = {}; GL(s, 1, TMP); WT(B0, s);
    f32x16 t = {}; GL(t, 7, B4); WT(B3, t); }
  __syncthreads();

  // J2 loop (src B4, ping B3/TMP), hat(J2) -> B4           [ph12..ph15]
  {
    f32x16 J = {};
    { f32x16 t = {}; GL(J, 7, B3); GL(t, 8, B4); WT(TMP, t); } __syncthreads();
    { f32x16 t = {}; GL(J, 8, TMP); GL(t, 9, B4); WT(B3, t); } __syncthreads();
    { f32x16 t = {}; GL(J, 9, B3); GL(t, 10, B4); WT(TMP, t); } __syncthreads();
    { GL(J, 10, TMP); WT(B4, J); } __syncthreads();
  }

  // ph16: hat(rho3) = Shat + 0.5dt*hat(J2) -> B0
  axpy(B0, B0, 0.5f * dt, B4, tid);
  __syncthreads();

  // J3 loop (src B0, ping TMP/B3), hat(J3) -> TMP          [ph17..ph21]
  {
    f32x16 J = {};
    { f32x16 t = {}; GL(t, 7, B0); WT(TMP, t); } __syncthreads();
    { f32x16 t = {}; GL(J, 7, TMP); GL(t, 8, B0); WT(B3, t); } __syncthreads();
    { f32x16 t = {}; GL(J, 8, B3); GL(t, 9, B0); WT(TMP, t); } __syncthreads();
    { f32x16 t = {}; GL(J, 9, TMP); GL(t, 10, B0); WT(B3, t); } __syncthreads();
    { GL(J, 10, B3); WT(TMP, J); } __syncthreads();
  }

  // ph22: t4 = Um1@J3 -> B0 ; tJJ = t4 + Um1@J2 -> B3
  { f32x16 a = {}; GL(a, 2, TMP); f32x16 c = a; GL(c, 2, B4);
    WT(B0, a); WT(B3, c); }
  __syncthreads();

  // ph23: out += dt/3 * tJJ@Um1^T ; hat(rho4) = hat(P) + dt*(Um1@t4^T) (rmw B1)
  { f32x16 s = {}; LG(s, B3, 2); outacc += (dt / 3.f) * s;
    f32x16 q = {}; GL(q, 2, B0); wtile_rmw(B1, ti, slotc, coff, lh, q, dt); }
  __syncthreads();

  // final jump Ls1 on rho4 (src B1, ping TMP/B4), plain    [ph24..ph28]
  {
    f32x16 J = {};
    { f32x16 t = {}; GL(t, 11, B1); WT(TMP, t); } __syncthreads();
    { f32x16 t = {}; LG(J, TMP, 11); GL(t, 12, B1); WT(B4, t); } __syncthreads();
    { f32x16 t = {}; LG(J, B4, 12); GL(t, 13, B1); WT(TMP, t); } __syncthreads();
    { f32x16 t = {}; LG(J, TMP, 13); GL(t, 14, B1); WT(B4, t); } __syncthreads();
    { LG(J, B4, 14); outacc += (dt / 6.f) * J; }
  }

  // store fp32 output tile
  {
    float* op = outg + b * 4096 + (size_t)(ti * 32 + lh * 4) * 64 + tj * 32 + l31;
#pragma unroll
    for (int r = 0; r < 16; ++r) {
      int row = (r & 3) + 8 * (r >> 2);
      op[row * 64] = outacc[r];
    }
  }
}

extern "C" void kernel_launch(void* const* d_in, const int* in_sizes, int n_in,
                              void* d_out, int out_size, void* d_ws, size_t ws_size,
                              hipStream_t stream) {
  const float* rho0 = (const float*)d_in[0];
  const float* U1 = (const float*)d_in[1];
  const float* Um = (const float*)d_in[2];
  const float* Ls0 = (const float*)d_in[3];
  const float* Lsmid = (const float*)d_in[4];
  const float* Ls1 = (const float*)d_in[5];
  const float* dtp = (const float*)d_in[6];
  float* out = (float*)d_out;
  float* ws = (float*)d_ws;   // [0,16KB): Um1 fp32; [16KB,136KB): bf16 frags

  const int B = in_sizes[0] >> 12;

  kraus_invert<<<1, 256, 0, stream>>>(U1, Um, ws);
  kraus_prepack<<<15, 256, 0, stream>>>(U1, Um, Ls0, Lsmid, Ls1, ws);
  kraus_main<<<B, 256, 0, stream>>>(rho0, dtp, (const char*)d_ws + 16384, out);
}